// Round 12
// baseline (199.097 us; speedup 1.0000x reference)
//
#include <hip/hip_runtime.h>
#include <hip/hip_bf16.h>

#define BB 2
#define CC 128
#define NN 4096
#define KK 20

// workspace offsets, in floats (total ~14.5 MB)
#define WS_FLAG   0
#define WS_FCACC  16
#define WS_S1     32
#define WS_C1     96
#define WS_S2     160
#define WS_C2     224
#define WS_SUP    288
#define WS_CUP    416
#define WS_FS     1024
#define WS_X      8192
#define WS_W1     40960
#define WS_W2T    41344      /* W2 transposed: [c<256][o<64] */
#define WS_WD1    57728
#define WS_WD2    59776
#define WS_WUP    61824
#define WS_P      65536
#define WS_Q      1114112
#define WS_FE     2326528
#define WS_F12    3375104

struct InPtrs { const void* p[22]; };

__device__ __forceinline__ int detect_bf16(const void* xyz) {
  const unsigned* u = (const unsigned*)xyz;
  int cnt = 0;
  for (int i = 0; i < 64; ++i) {
    unsigned lo = u[i] & 0x7FFFu;
    cnt += (lo >= 0x3C00u && lo <= 0x4100u) ? 1 : 0;
  }
  return cnt >= 32;
}

__device__ __forceinline__ float ldin(const void* p, long long i, int flag) {
  if (flag) {
    unsigned short b = ((const unsigned short*)p)[i];
    return __uint_as_float(((unsigned)b) << 16);
  }
  return ((const float*)p)[i];
}

// order-preserving f32 -> u32 (exact): monotone for all finite floats
__device__ __forceinline__ unsigned sortable(float v) {
  unsigned u = __float_as_uint(v);
  return (u & 0x80000000u) ? ~u : (u | 0x80000000u);
}

// wave-wide max of u32 via DPP reduction chain; uniform result via readlane 63.
__device__ __forceinline__ unsigned wave_max_u32(unsigned x) {
  unsigned t;
  t = (unsigned)__builtin_amdgcn_update_dpp(0, (int)x, 0x111, 0xF, 0xF, true); x = x > t ? x : t; // row_shr:1
  t = (unsigned)__builtin_amdgcn_update_dpp(0, (int)x, 0x112, 0xF, 0xF, true); x = x > t ? x : t; // row_shr:2
  t = (unsigned)__builtin_amdgcn_update_dpp(0, (int)x, 0x114, 0xF, 0xF, true); x = x > t ? x : t; // row_shr:4
  t = (unsigned)__builtin_amdgcn_update_dpp(0, (int)x, 0x118, 0xF, 0xF, true); x = x > t ? x : t; // row_shr:8
  t = (unsigned)__builtin_amdgcn_update_dpp(0, (int)x, 0x142, 0xF, 0xF, true); x = x > t ? x : t; // row_bcast:15
  t = (unsigned)__builtin_amdgcn_update_dpp(0, (int)x, 0x143, 0xF, 0xF, true); x = x > t ? x : t; // row_bcast:31
  return (unsigned)__builtin_amdgcn_readlane((int)x, 63);
}

// sorted-descending top-4 insert of (pd,idx) on FLOAT keys; strict '>' keeps
// idx-ascending order among equal pds (stream feeds ascending idx) -> matches
// lax.top_k ties. NaN impossible (finite inputs); -0.0 impossible (final op
// a-xxm yields +0 when equal, negative nonzero otherwise). Float '>' ordering
// is identical to sortable-u32 '>' (monotone bijection) -> winner sets match
// the proven u32 baseline bit-for-bit.
__device__ __forceinline__ void insert4f(float pd, int idx,
    float& p0, int& i0, float& p1, int& i1,
    float& p2, int& i2, float& p3, int& i3) {
  bool b0 = pd > p0, b1 = pd > p1, b2 = pd > p2, b3 = pd > p3;
  p3 = b3 ? (b2 ? p2 : pd) : p3;  i3 = b3 ? (b2 ? i2 : idx) : i3;
  p2 = b2 ? (b1 ? p1 : pd) : p2;  i2 = b2 ? (b1 ? i1 : idx) : i2;
  p1 = b1 ? (b0 ? p0 : pd) : p1;  i1 = b1 ? (b0 ? i0 : idx) : i1;
  p0 = b0 ? pd : p0;              i0 = b0 ? idx : i0;
}

// ---- k0: dtype detect + stage small tensors + W2 transpose + fold BN params --
__global__ __launch_bounds__(256) void k0_convert(InPtrs in, float* ws) {
  int flag = detect_bf16(in.p[0]);
  int gid = blockIdx.x * 256 + threadIdx.x;
  int stride = gridDim.x * 256;
  // W2 transpose: W2T[c][o] = W2[o][c]
  for (int i = gid; i < 16384; i += stride) {
    int c = i >> 6, o = i & 63;
    ws[WS_W2T + i] = ldin(in.p[8], o * 256 + c, flag);
  }
  // xyz + small weight matrices
  const int T0 = 24576;           // xyz end
  const int T1 = T0 + 384;        // w_mlp1 end
  const int T2 = T1 + 2048;       // w_down1 end
  const int T3 = T2 + 2048;       // w_down2 end
  const int T4 = T3 + 2048;       // w_up end (31104)
  for (int i = gid; i < T4; i += stride) {
    const void* src; int off, dst;
    if      (i < T0) { src = in.p[0];  off = i;      dst = WS_X   + off; }
    else if (i < T1) { src = in.p[2];  off = i - T0; dst = WS_W1  + off; }
    else if (i < T2) { src = in.p[14]; off = i - T1; dst = WS_WD1 + off; }
    else if (i < T3) { src = in.p[15]; off = i - T2; dst = WS_WD2 + off; }
    else             { src = in.p[16]; off = i - T3; dst = WS_WUP + off; }
    ws[dst] = ldin(src, off, flag);
  }
  if (blockIdx.x == 0) {
    int t = threadIdx.x;
    if (t < 64) {
      float b1 = ldin(in.p[3], t, flag), g1 = ldin(in.p[4], t, flag);
      float be1 = ldin(in.p[5], t, flag), m1 = ldin(in.p[6], t, flag), v1 = ldin(in.p[7], t, flag);
      float s1 = g1 / sqrtf(v1 + 1e-5f);
      ws[WS_S1 + t] = s1;
      ws[WS_C1 + t] = s1 * (b1 - m1) + be1;
      float b2 = ldin(in.p[9], t, flag), g2 = ldin(in.p[10], t, flag);
      float be2 = ldin(in.p[11], t, flag), m2 = ldin(in.p[12], t, flag), v2 = ldin(in.p[13], t, flag);
      float s2 = g2 / sqrtf(v2 + 1e-5f);
      ws[WS_S2 + t] = s2;
      ws[WS_C2 + t] = s2 * (b2 - m2) + be2;
    }
    if (t < 128) {
      float bu = ldin(in.p[17], t, flag), gu = ldin(in.p[18], t, flag);
      float beu = ldin(in.p[19], t, flag), mu = ldin(in.p[20], t, flag), vu = ldin(in.p[21], t, flag);
      float su = gu / sqrtf(vu + 1e-5f);
      ws[WS_SUP + t] = su;
      ws[WS_CUP + t] = su * (bu - mu) + beu;
    }
    if (t < 16) ws[WS_FCACC + t] = 0.f;
    if (t == 0) ((int*)ws)[WS_FLAG] = flag;
  }
}

// ---------------- k1: P,Q projections — features read inline (no F staging) ---
// 1024 blocks = 2b x 64mt x 8ot; o0 = ot*8 + w*2 (wave-uniform), float2 stores.
// XX store removed: k23 recomputes ||x||^2 inline (bit-identical formula).
__global__ __launch_bounds__(256) void k1_pq(InPtrs in, float* ws) {
  int t = threadIdx.x;
  int bid = blockIdx.x;              // 1024 = 2b x 64mt x 8ot
  int b = bid >> 9;
  int mt = (bid >> 3) & 63;
  int ot = bid & 7;
  int w = __builtin_amdgcn_readfirstlane(t >> 6);
  int lane = t & 63;
  int o0 = ot * 8 + w * 2;           // wave-uniform
  int m = (mt << 6) + lane;
  int flag = ((const int*)ws)[WS_FLAG];
  const float* W2T = ws + WS_W2T;
  float accP[2] = {0.f, 0.f}, accQ[2] = {0.f, 0.f};
  long long fb = (long long)b * CC * NN + m;
#define K1_BODY(FVAL)                                            \
    {                                                            \
      float f = (FVAL);                                          \
      accP[0] = fmaf(W2T[c * 64 + o0 + 0], f, accP[0]);          \
      accP[1] = fmaf(W2T[c * 64 + o0 + 1], f, accP[1]);          \
      accQ[0] = fmaf(W2T[(128 + c) * 64 + o0 + 0], f, accQ[0]);  \
      accQ[1] = fmaf(W2T[(128 + c) * 64 + o0 + 1], f, accQ[1]);  \
    }
  if (flag) {
    const unsigned short* F = (const unsigned short*)in.p[1] + fb;
#pragma unroll 8
    for (int c = 0; c < 128; ++c)
      K1_BODY(__uint_as_float(((unsigned)F[(long long)c * NN]) << 16))
  } else {
    const float* F = (const float*)in.p[1] + fb;
#pragma unroll 8
    for (int c = 0; c < 128; ++c)
      K1_BODY(F[(long long)c * NN])
  }
#undef K1_BODY
  const float* X = ws + WS_X + (long long)b * 3 * NN;
  float x0 = X[m], x1 = X[NN + m], x2 = X[2 * NN + m];
  const float* W1 = ws + WS_W1;
  float* P = ws + WS_P + ((long long)(b * NN + m)) * 128;
  float* Q = ws + WS_Q + ((long long)(b * NN + m)) * 128;
  float2 p1v, q1v, p2v, q2v;
#pragma unroll
  for (int j = 0; j < 2; ++j) {
    int o = o0 + j;
    float s1 = ws[WS_S1 + o], c1 = ws[WS_C1 + o];
    float px = fmaf(W1[o * 6 + 2], x2, fmaf(W1[o * 6 + 1], x1, W1[o * 6 + 0] * x0));
    float qx = fmaf(W1[o * 6 + 5], x2, fmaf(W1[o * 6 + 4], x1, W1[o * 6 + 3] * x0));
    (&p1v.x)[j] = s1 * px;
    (&q1v.x)[j] = fmaf(s1, qx - px, c1);
    float s2 = ws[WS_S2 + o], c2 = ws[WS_C2 + o];
    (&p2v.x)[j] = s2 * accP[j];
    (&q2v.x)[j] = fmaf(s2, accQ[j] - accP[j], c2);
  }
  *(float2*)(P + o0)      = p1v;
  *(float2*)(P + 64 + o0) = p2v;
  *(float2*)(Q + o0)      = q1v;
  *(float2*)(Q + 64 + o0) = q2v;
}

// ------- k23: KNN top-20 (float insert keys, u32 wave-max) + gather -----------
// Deltas vs R11 (passing), both bit-identical by construction:
// (1) ||x||^2 recomputed inline with k1's exact formula (XX array removed):
//     trades 1 VMEM + addressing for 5 VALU per candidate.
// (2) per-candidate sortable() dropped; insert keys stay float (strict '>' ==
//     sortable-u32 ordering); selection converts only the head per round and
//     keeps the proven u32 DPP chain + ballot fast path.
__global__ __launch_bounds__(256) void k23_knn_fenc(float* ws) {
  int t = threadIdx.x;
  int w = t >> 6, lane = t & 63;
  int pt = blockIdx.x * 4 + w;                // 2048 blocks, 1 wave = 1 point
  int b = pt >> 12;
  int n = pt & (NN - 1);
  const float* X = ws + WS_X + (long long)b * 3 * NN;
  float xc0 = X[n], xc1 = X[NN + n], xc2 = X[2 * NN + n];
  float xxn = __fadd_rn(__fadd_rn(__fmul_rn(xc0, xc0), __fmul_rn(xc1, xc1)), __fmul_rn(xc2, xc2));
  const float NEG = -3.4028235e38f;
  float p0 = NEG, p1 = NEG, p2 = NEG, p3 = NEG;
  int i0 = 0, i1 = 0, i2 = 0, i3 = 0;
#pragma unroll 8
  for (int s = 0; s < 64; ++s) {
    int m = s * 64 + lane;
    float c0 = X[m], c1 = X[NN + m], c2 = X[2 * NN + m];
    float xxm = __fadd_rn(__fadd_rn(__fmul_rn(c0, c0), __fmul_rn(c1, c1)), __fmul_rn(c2, c2));
    float inner = __fadd_rn(__fadd_rn(__fmul_rn(c0, xc0), __fmul_rn(c1, xc1)), __fmul_rn(c2, xc2));
    float pd = __fsub_rn(__fsub_rn(__fmul_rn(2.0f, inner), xxn), xxm);
    insert4f(pd, m, p0, i0, p1, i1, p2, i2, p3, i3);
  }
  unsigned long long used = 0;
  int nv = 4;
  int winner = 0;                             // lane r keeps round-r winner index
  for (int r = 0; r < KK; ++r) {
    unsigned key = sortable(p0);
    unsigned spd = wave_max_u32(key);         // max pd among heads (uniform)
    unsigned long long msk = __ballot(key == spd);
    int sidx;
    if (__popcll(msk) == 1) {                 // fast path: unique owner lane
      sidx = __builtin_amdgcn_readlane(i0, (int)(__ffsll((long long)msk) - 1));
    } else {                                  // exact-tie: min idx among ties
      unsigned cand = (key == spd) ? (unsigned)(4095 - i0) : 0u;
      sidx = (int)(4095u - wave_max_u32(cand));
    }
    if (lane == r) winner = sidx;
    if (key == spd && i0 == sidx) {           // unique owner lane pops its head
      used |= 1ull << (i0 >> 6);
      p0 = p1; i0 = i1; p1 = p2; i1 = i2; p2 = p3; i2 = i3; p3 = NEG; i3 = 0;
      if (--nv == 0) {                        // rare: lane supplied >=5 winners
        p0 = p1 = p2 = p3 = NEG; i0 = i1 = i2 = i3 = 0;
#pragma unroll 1
        for (int s = 0; s < 64; ++s) {
          if (!((used >> s) & 1ull)) {
            int m = s * 64 + lane;
            float c0 = X[m], c1 = X[NN + m], c2 = X[2 * NN + m];
            float xxm = __fadd_rn(__fadd_rn(__fmul_rn(c0, c0), __fmul_rn(c1, c1)), __fmul_rn(c2, c2));
            float inner = __fadd_rn(__fadd_rn(__fmul_rn(c0, xc0), __fmul_rn(c1, xc1)), __fmul_rn(c2, xc2));
            float pd = __fsub_rn(__fsub_rn(__fmul_rn(2.0f, inner), xxn), xxm);
            insert4f(pd, m, p0, i0, p1, i1, p2, i2, p3, i3);
          }
        }
        nv = 4;
      }
    }
  }
  // gather + max-pool: hoist all neighbor ids first, then 20 independent loads
  const float* Q = ws + WS_Q + (long long)pt * 128;
  const float* Pb = ws + WS_P + (long long)b * NN * 128;
  float2 q = ((const float2*)Q)[lane];
  int ids[KK];
#pragma unroll
  for (int j = 0; j < KK; ++j) ids[j] = __shfl(winner, j);
  float mx0 = -3.4e38f, mx1 = -3.4e38f;
#pragma unroll
  for (int j = 0; j < KK; ++j) {
    float2 p = ((const float2*)(Pb + (long long)ids[j] * 128))[lane];
    mx0 = fmaxf(mx0, p.x + q.x);
    mx1 = fmaxf(mx1, p.y + q.y);
  }
  float2 fe = make_float2(fmaxf(mx0, 0.f), fmaxf(mx1, 0.f));
  ((float2*)(ws + WS_FE + (long long)pt * 128))[lane] = fe;
}

// ---------------- k4: down-projections f1,f2 + f_space + f_channel accum ------
__global__ __launch_bounds__(256) void k4_down(float* ws) {
  __shared__ float ldsFE[8 * 128];
  __shared__ float ldsW[32 * 129];
  __shared__ float ldsFC[16];
  int t = threadIdx.x;
  int b = blockIdx.x >> 9;
  int n0 = (blockIdx.x & 511) << 3;
  for (int i = t; i < 8 * 128; i += 256) {
    int p = i >> 7, c = i & 127;
    ldsFE[i] = ws[WS_FE + (long long)(b * NN + n0 + p) * 128 + c];
  }
  for (int i = t; i < 32 * 128; i += 256) {
    int o = i >> 7, c = i & 127;
    ldsW[o * 129 + c] = (o < 16) ? ws[WS_WD1 + o * 128 + c] : ws[WS_WD2 + (o - 16) * 128 + c];
  }
  if (t < 16) ldsFC[t] = 0.f;
  __syncthreads();
  int p = t >> 5, oid = t & 31;
  float acc = 0.f;
#pragma unroll 8
  for (int c = 0; c < 128; ++c)
    acc = fmaf(ldsW[oid * 129 + c], ldsFE[p * 128 + c], acc);
  float v = fmaxf(acc, 0.f);
  ws[WS_F12 + (long long)(b * NN + n0 + p) * 32 + oid] = v;
  if (b == 0) {
    if (oid >= 16) {
      float s = v;
#pragma unroll
      for (int d = 1; d < 16; d <<= 1) s += __shfl_xor(s, d);
      if (oid == 16) ws[WS_FS + n0 + p] = s * 0.0625f;
    } else {
      atomicAdd(&ldsFC[oid], v);
    }
  }
  __syncthreads();
  if (b == 0 && t < 16) atomicAdd(ws + WS_FCACC + t, ldsFC[t]);
}

// ---------------- k5: outer-sqrt + up-proj + BN + Mish -> output --------------
__global__ __launch_bounds__(256) void k5_final(float* ws, float* outf, __hip_bfloat16* outb) {
  __shared__ float fin[16 * 16];
  int t = threadIdx.x;
  int g = t >> 4;        // 0..15 : output group of 8
  int p = t & 15;        // point within tile
  int b = blockIdx.x >> 8;
  int n0 = (blockIdx.x & 255) << 4;
  int n = n0 + p;
  int flag = ((const int*)ws)[WS_FLAG];
  {
    float fs = ws[WS_FS + n];
    float fc = ws[WS_FCACC + g] * (1.0f / NN);
    float f1v = ws[WS_F12 + (long long)(b * NN + n) * 32 + g];
    float f2v = ws[WS_F12 + (long long)(b * NN + n) * 32 + 16 + g];
    fin[p * 16 + g] = sqrtf(fc * fs + 1e-12f) + f1v + f2v;
  }
  __syncthreads();
  const float4* FE4 = (const float4*)(ws + WS_FE + (long long)(b * NN + n) * 128 + g * 8);
  float fev[8];
  {
    float4 a = FE4[0], c = FE4[1];
    fev[0] = a.x; fev[1] = a.y; fev[2] = a.z; fev[3] = a.w;
    fev[4] = c.x; fev[5] = c.y; fev[6] = c.z; fev[7] = c.w;
  }
#pragma unroll
  for (int j = 0; j < 8; ++j) {
    int o = g * 8 + j;
    float acc = 0.f;
#pragma unroll
    for (int c = 0; c < 16; ++c)
      acc = fmaf(ws[WS_WUP + o * 16 + c], fin[p * 16 + c], acc);
    float fo = fmaf(ws[WS_SUP + o], acc, ws[WS_CUP + o]);
    fo = fmaxf(fo, 0.f);
    float fl = fev[j] - fo;
    // Mish(x) = x*(u^2+2u)/(u^2+2u+2), u=e^x; exact for x<=15, y=x beyond
    float u = __expf(fl);
    float nmr = u * (u + 2.f);
    float y = fl * __fdividef(nmr, nmr + 2.f);
    if (fl > 15.f) y = fl;
    long long oi = ((long long)b * CC + o) * NN + n;
    if (flag) outb[oi] = __float2bfloat16(y);
    else      outf[oi] = y;
  }
}

extern "C" void kernel_launch(void* const* d_in, const int* in_sizes, int n_in,
                              void* d_out, int out_size, void* d_ws, size_t ws_size,
                              hipStream_t stream) {
  (void)in_sizes; (void)out_size; (void)ws_size;
  float* ws = (float*)d_ws;
  InPtrs ip;
  for (int i = 0; i < 22; ++i) ip.p[i] = (i < n_in) ? d_in[i] : nullptr;
  hipLaunchKernelGGL(k0_convert,   dim3(128),          dim3(256), 0, stream, ip, ws);
  hipLaunchKernelGGL(k1_pq,        dim3(1024),         dim3(256), 0, stream, ip, ws);
  hipLaunchKernelGGL(k23_knn_fenc, dim3(BB * NN / 4),  dim3(256), 0, stream, ws);
  hipLaunchKernelGGL(k4_down,      dim3(BB * NN / 8),  dim3(256), 0, stream, ws);
  hipLaunchKernelGGL(k5_final,     dim3(BB * NN / 16), dim3(256), 0, stream, ws,
                     (float*)d_out, (__hip_bfloat16*)d_out);
}

// Round 13
// 190.898 us; speedup vs baseline: 1.0429x; 1.0429x over previous
//
#include <hip/hip_runtime.h>
#include <hip/hip_bf16.h>

#define BB 2
#define CC 128
#define NN 4096
#define KK 20

// workspace offsets, in floats
#define WS_FLAG   0
#define WS_FCACC  16
#define WS_SUP    288
#define WS_CUP    416
#define WS_FS     1024
#define WS_X      8192
#define WS_XX     32768
#define WS_WD1    57728
#define WS_WD2    59776
#define WS_WUP    61824
#define WS_P      65536
#define WS_Q      1114112
#define WS_FE     2326528
#define WS_F12    3375104

struct InPtrs { const void* p[22]; };

__device__ __forceinline__ float ldin(const void* p, long long i, int flag) {
  if (flag) {
    unsigned short b = ((const unsigned short*)p)[i];
    return __uint_as_float(((unsigned)b) << 16);
  }
  return ((const float*)p)[i];
}

// order-preserving f32 -> u32 (exact): monotone for all finite floats
__device__ __forceinline__ unsigned sortable(float v) {
  unsigned u = __float_as_uint(v);
  return (u & 0x80000000u) ? ~u : (u | 0x80000000u);
}

// wave-wide max of u32 via DPP reduction chain; uniform result via readlane 63.
__device__ __forceinline__ unsigned wave_max_u32(unsigned x) {
  unsigned t;
  t = (unsigned)__builtin_amdgcn_update_dpp(0, (int)x, 0x111, 0xF, 0xF, true); x = x > t ? x : t; // row_shr:1
  t = (unsigned)__builtin_amdgcn_update_dpp(0, (int)x, 0x112, 0xF, 0xF, true); x = x > t ? x : t; // row_shr:2
  t = (unsigned)__builtin_amdgcn_update_dpp(0, (int)x, 0x114, 0xF, 0xF, true); x = x > t ? x : t; // row_shr:4
  t = (unsigned)__builtin_amdgcn_update_dpp(0, (int)x, 0x118, 0xF, 0xF, true); x = x > t ? x : t; // row_shr:8
  t = (unsigned)__builtin_amdgcn_update_dpp(0, (int)x, 0x142, 0xF, 0xF, true); x = x > t ? x : t; // row_bcast:15
  t = (unsigned)__builtin_amdgcn_update_dpp(0, (int)x, 0x143, 0xF, 0xF, true); x = x > t ? x : t; // row_bcast:31
  return (unsigned)__builtin_amdgcn_readlane((int)x, 63);
}

// sorted-descending top-4 insert of (pd,idx); strict '>' keeps idx-ascending
// order among equal pds (stream feeds ascending idx) -> matches lax.top_k ties.
__device__ __forceinline__ void insert4p(unsigned pd, int idx,
    unsigned& p0, int& i0, unsigned& p1, int& i1,
    unsigned& p2, int& i2, unsigned& p3, int& i3) {
  bool b0 = pd > p0, b1 = pd > p1, b2 = pd > p2, b3 = pd > p3;
  p3 = b3 ? (b2 ? p2 : pd) : p3;  i3 = b3 ? (b2 ? i2 : idx) : i3;
  p2 = b2 ? (b1 ? p1 : pd) : p2;  i2 = b2 ? (b1 ? i1 : idx) : i2;
  p1 = b1 ? (b0 ? p0 : pd) : p1;  i1 = b1 ? (b0 ? i0 : idx) : i1;
  p0 = b0 ? pd : p0;              i0 = b0 ? idx : i0;
}

// ---- k1: fused staging + P,Q projections (k0 absorbed; 4 launches total) -----
// 1024 blocks = 2b x 64mt x 8ot. Per block: flag via wave ballot (bit-identical
// to the old per-thread count), 8 W2 rows staged to LDS as (P,Q) float2 pairs,
// residual global staging (X, WD1/2, WUP, SUP/CUP folds, FLAG, FCACC) done by
// blocks 0..127 before their own work. All values use the same ldin conversion
// and fold formulas as the old k0 -> bit-identical dataflow.
__global__ __launch_bounds__(256) void k1_pq(InPtrs in, float* ws) {
  __shared__ float ldsW2[8 * 128 * 2];        // 8 KB: [row(8)][c(128)][P|Q]
  int t = threadIdx.x;
  int bid = blockIdx.x;              // 1024 = 2b x 64mt x 8ot
  int b = bid >> 9;
  int mt = (bid >> 3) & 63;
  int ot = bid & 7;
  int lane = t & 63;
  // flag: lane i tests word i of xyz (same predicate + count as detect_bf16)
  unsigned xw = ((const unsigned*)in.p[0])[lane];
  unsigned lo = xw & 0x7FFFu;
  unsigned long long bm = __ballot(lo >= 0x3C00u && lo <= 0x4100u);
  int flag = (__popcll(bm) >= 32) ? 1 : 0;    // wave-uniform
  // stage this block's 8 W2 rows: lds[(r*128+col)*2 + half] = W2[ot*8+r][half*128+col]
  for (int i = t; i < 2048; i += 256) {
    int r = i >> 8, cc = i & 255;
    ldsW2[((r * 128 + (cc & 127)) << 1) + (cc >> 7)] =
        ldin(in.p[8], (ot * 8 + r) * 256 + cc, flag);
  }
  // residual staging for k23/k4/k5
  if (bid < 128) {
    int gid = bid * 256 + t;
    if      (gid < 24576) ws[WS_X   + gid]         = ldin(in.p[0],  gid,         flag);
    else if (gid < 26624) ws[WS_WD1 + gid - 24576] = ldin(in.p[14], gid - 24576, flag);
    else if (gid < 28672) ws[WS_WD2 + gid - 26624] = ldin(in.p[15], gid - 26624, flag);
    else if (gid < 30720) ws[WS_WUP + gid - 28672] = ldin(in.p[16], gid - 28672, flag);
    if (bid == 0) {
      if (t < 128) {
        float bu = ldin(in.p[17], t, flag), gu = ldin(in.p[18], t, flag);
        float beu = ldin(in.p[19], t, flag), mu = ldin(in.p[20], t, flag), vu = ldin(in.p[21], t, flag);
        float su = gu / sqrtf(vu + 1e-5f);
        ws[WS_SUP + t] = su;
        ws[WS_CUP + t] = su * (bu - mu) + beu;
      }
      if (t < 16) ws[WS_FCACC + t] = 0.f;
      if (t == 0) ((int*)ws)[WS_FLAG] = flag;
    }
  }
  __syncthreads();
  int w = __builtin_amdgcn_readfirstlane(t >> 6);
  int o0 = ot * 8 + w * 2;           // wave-uniform
  int m = (mt << 6) + lane;
  const float2* w2r0 = (const float2*)ldsW2 + (w * 2) * 128;
  const float2* w2r1 = (const float2*)ldsW2 + (w * 2 + 1) * 128;
  float accP[2] = {0.f, 0.f}, accQ[2] = {0.f, 0.f};
  long long fb = (long long)b * CC * NN + m;
#define K1_BODY(FVAL)                                  \
    {                                                  \
      float f = (FVAL);                                \
      float2 v0 = w2r0[c], v1 = w2r1[c];               \
      accP[0] = fmaf(v0.x, f, accP[0]);                \
      accQ[0] = fmaf(v0.y, f, accQ[0]);                \
      accP[1] = fmaf(v1.x, f, accP[1]);                \
      accQ[1] = fmaf(v1.y, f, accQ[1]);                \
    }
  if (flag) {
    const unsigned short* F = (const unsigned short*)in.p[1] + fb;
#pragma unroll 8
    for (int c = 0; c < 128; ++c)
      K1_BODY(__uint_as_float(((unsigned)F[(long long)c * NN]) << 16))
  } else {
    const float* F = (const float*)in.p[1] + fb;
#pragma unroll 8
    for (int c = 0; c < 128; ++c)
      K1_BODY(F[(long long)c * NN])
  }
#undef K1_BODY
  long long xb = (long long)b * 3 * NN;
  float x0 = ldin(in.p[0], xb + m, flag);
  float x1 = ldin(in.p[0], xb + NN + m, flag);
  float x2 = ldin(in.p[0], xb + 2 * NN + m, flag);
  float* P = ws + WS_P + ((long long)(b * NN + m)) * 128;
  float* Q = ws + WS_Q + ((long long)(b * NN + m)) * 128;
  float2 p1v, q1v, p2v, q2v;
#pragma unroll
  for (int j = 0; j < 2; ++j) {
    int o = o0 + j;
    float b1 = ldin(in.p[3], o, flag), g1 = ldin(in.p[4], o, flag);
    float be1 = ldin(in.p[5], o, flag), m1 = ldin(in.p[6], o, flag), v1 = ldin(in.p[7], o, flag);
    float s1 = g1 / sqrtf(v1 + 1e-5f);
    float c1 = s1 * (b1 - m1) + be1;
    float b2 = ldin(in.p[9], o, flag), g2 = ldin(in.p[10], o, flag);
    float be2 = ldin(in.p[11], o, flag), m2 = ldin(in.p[12], o, flag), v2 = ldin(in.p[13], o, flag);
    float s2 = g2 / sqrtf(v2 + 1e-5f);
    float c2 = s2 * (b2 - m2) + be2;
    float w10 = ldin(in.p[2], o * 6 + 0, flag), w11 = ldin(in.p[2], o * 6 + 1, flag);
    float w12 = ldin(in.p[2], o * 6 + 2, flag), w13 = ldin(in.p[2], o * 6 + 3, flag);
    float w14 = ldin(in.p[2], o * 6 + 4, flag), w15 = ldin(in.p[2], o * 6 + 5, flag);
    float px = fmaf(w12, x2, fmaf(w11, x1, w10 * x0));
    float qx = fmaf(w15, x2, fmaf(w14, x1, w13 * x0));
    (&p1v.x)[j] = s1 * px;
    (&q1v.x)[j] = fmaf(s1, qx - px, c1);
    (&p2v.x)[j] = s2 * accP[j];
    (&q2v.x)[j] = fmaf(s2, accQ[j] - accP[j], c2);
  }
  *(float2*)(P + o0)      = p1v;
  *(float2*)(P + 64 + o0) = p2v;
  *(float2*)(Q + o0)      = q1v;
  *(float2*)(Q + 64 + o0) = q2v;
  if (ot == 0 && w == 0) {
    float xx = __fadd_rn(__fadd_rn(__fmul_rn(x0, x0), __fmul_rn(x1, x1)), __fmul_rn(x2, x2));
    ws[WS_XX + b * NN + m] = xx;
  }
}

// ------- k23: KNN top-20 (u32 keys + DPP wave-max) + gather + max-pool --------
// Frozen at measured-best R8/R11 form: no LDS, sortable-u32 scan keys, ballot
// fast-path selection, hoisted gather ids. Six structural variants land in
// 60-63 us -> this kernel is at its dependency-latency structural floor.
__global__ __launch_bounds__(256) void k23_knn_fenc(float* ws) {
  int t = threadIdx.x;
  int w = t >> 6, lane = t & 63;
  int pt = blockIdx.x * 4 + w;                // 2048 blocks, 1 wave = 1 point
  int b = pt >> 12;
  int n = pt & (NN - 1);
  const float* X = ws + WS_X + (long long)b * 3 * NN;
  const float* XX = ws + WS_XX + (long long)b * NN;
  float xc0 = X[n], xc1 = X[NN + n], xc2 = X[2 * NN + n], xxn = XX[n];
  unsigned p0 = 0, p1 = 0, p2 = 0, p3 = 0;
  int i0 = 0, i1 = 0, i2 = 0, i3 = 0;
#pragma unroll 8
  for (int s = 0; s < 64; ++s) {
    int m = s * 64 + lane;
    float c0 = X[m], c1 = X[NN + m], c2 = X[2 * NN + m], xxm = XX[m];
    float inner = __fadd_rn(__fadd_rn(__fmul_rn(c0, xc0), __fmul_rn(c1, xc1)), __fmul_rn(c2, xc2));
    float pd = __fsub_rn(__fsub_rn(__fmul_rn(2.0f, inner), xxn), xxm);
    insert4p(sortable(pd), m, p0, i0, p1, i1, p2, i2, p3, i3);
  }
  unsigned long long used = 0;
  int nv = 4;
  int winner = 0;                             // lane r keeps round-r winner index
  for (int r = 0; r < KK; ++r) {
    unsigned spd = wave_max_u32(p0);          // max pd among heads (uniform)
    unsigned long long msk = __ballot(p0 == spd);
    int sidx;
    if (__popcll(msk) == 1) {                 // fast path: unique owner lane
      sidx = __builtin_amdgcn_readlane(i0, (int)(__ffsll((long long)msk) - 1));
    } else {                                  // exact-tie: min idx among ties
      unsigned cand = (p0 == spd) ? (unsigned)(4095 - i0) : 0u;
      sidx = (int)(4095u - wave_max_u32(cand));
    }
    if (lane == r) winner = sidx;
    if (p0 == spd && i0 == sidx) {            // unique owner lane pops its head
      used |= 1ull << (i0 >> 6);
      p0 = p1; i0 = i1; p1 = p2; i1 = i2; p2 = p3; i2 = i3; p3 = 0; i3 = 0;
      if (--nv == 0) {                        // rare: lane supplied >=5 winners
        p0 = p1 = p2 = p3 = 0; i0 = i1 = i2 = i3 = 0;
#pragma unroll 1
        for (int s = 0; s < 64; ++s) {
          if (!((used >> s) & 1ull)) {
            int m = s * 64 + lane;
            float c0 = X[m], c1 = X[NN + m], c2 = X[2 * NN + m], xxm = XX[m];
            float inner = __fadd_rn(__fadd_rn(__fmul_rn(c0, xc0), __fmul_rn(c1, xc1)), __fmul_rn(c2, xc2));
            float pd = __fsub_rn(__fsub_rn(__fmul_rn(2.0f, inner), xxn), xxm);
            insert4p(sortable(pd), m, p0, i0, p1, i1, p2, i2, p3, i3);
          }
        }
        nv = 4;
      }
    }
  }
  // gather + max-pool: hoist all neighbor ids first, then 20 independent loads
  const float* Q = ws + WS_Q + (long long)pt * 128;
  const float* Pb = ws + WS_P + (long long)b * NN * 128;
  float2 q = ((const float2*)Q)[lane];
  int ids[KK];
#pragma unroll
  for (int j = 0; j < KK; ++j) ids[j] = __shfl(winner, j);
  float mx0 = -3.4e38f, mx1 = -3.4e38f;
#pragma unroll
  for (int j = 0; j < KK; ++j) {
    float2 p = ((const float2*)(Pb + (long long)ids[j] * 128))[lane];
    mx0 = fmaxf(mx0, p.x + q.x);
    mx1 = fmaxf(mx1, p.y + q.y);
  }
  float2 fe = make_float2(fmaxf(mx0, 0.f), fmaxf(mx1, 0.f));
  ((float2*)(ws + WS_FE + (long long)pt * 128))[lane] = fe;
}

// ---------------- k4: down-projections f1,f2 + f_space + f_channel accum ------
__global__ __launch_bounds__(256) void k4_down(float* ws) {
  __shared__ float ldsFE[8 * 128];
  __shared__ float ldsW[32 * 129];
  __shared__ float ldsFC[16];
  int t = threadIdx.x;
  int b = blockIdx.x >> 9;
  int n0 = (blockIdx.x & 511) << 3;
  for (int i = t; i < 8 * 128; i += 256) {
    int p = i >> 7, c = i & 127;
    ldsFE[i] = ws[WS_FE + (long long)(b * NN + n0 + p) * 128 + c];
  }
  for (int i = t; i < 32 * 128; i += 256) {
    int o = i >> 7, c = i & 127;
    ldsW[o * 129 + c] = (o < 16) ? ws[WS_WD1 + o * 128 + c] : ws[WS_WD2 + (o - 16) * 128 + c];
  }
  if (t < 16) ldsFC[t] = 0.f;
  __syncthreads();
  int p = t >> 5, oid = t & 31;
  float acc = 0.f;
#pragma unroll 8
  for (int c = 0; c < 128; ++c)
    acc = fmaf(ldsW[oid * 129 + c], ldsFE[p * 128 + c], acc);
  float v = fmaxf(acc, 0.f);
  ws[WS_F12 + (long long)(b * NN + n0 + p) * 32 + oid] = v;
  if (b == 0) {
    if (oid >= 16) {
      float s = v;
#pragma unroll
      for (int d = 1; d < 16; d <<= 1) s += __shfl_xor(s, d);
      if (oid == 16) ws[WS_FS + n0 + p] = s * 0.0625f;
    } else {
      atomicAdd(&ldsFC[oid], v);
    }
  }
  __syncthreads();
  if (b == 0 && t < 16) atomicAdd(ws + WS_FCACC + t, ldsFC[t]);
}

// ---------------- k5: outer-sqrt + up-proj + BN + Mish -> output --------------
__global__ __launch_bounds__(256) void k5_final(float* ws, float* outf, __hip_bfloat16* outb) {
  __shared__ float fin[16 * 16];
  int t = threadIdx.x;
  int g = t >> 4;        // 0..15 : output group of 8
  int p = t & 15;        // point within tile
  int b = blockIdx.x >> 8;
  int n0 = (blockIdx.x & 255) << 4;
  int n = n0 + p;
  int flag = ((const int*)ws)[WS_FLAG];
  {
    float fs = ws[WS_FS + n];
    float fc = ws[WS_FCACC + g] * (1.0f / NN);
    float f1v = ws[WS_F12 + (long long)(b * NN + n) * 32 + g];
    float f2v = ws[WS_F12 + (long long)(b * NN + n) * 32 + 16 + g];
    fin[p * 16 + g] = sqrtf(fc * fs + 1e-12f) + f1v + f2v;
  }
  __syncthreads();
  const float4* FE4 = (const float4*)(ws + WS_FE + (long long)(b * NN + n) * 128 + g * 8);
  float fev[8];
  {
    float4 a = FE4[0], c = FE4[1];
    fev[0] = a.x; fev[1] = a.y; fev[2] = a.z; fev[3] = a.w;
    fev[4] = c.x; fev[5] = c.y; fev[6] = c.z; fev[7] = c.w;
  }
#pragma unroll
  for (int j = 0; j < 8; ++j) {
    int o = g * 8 + j;
    float acc = 0.f;
#pragma unroll
    for (int c = 0; c < 16; ++c)
      acc = fmaf(ws[WS_WUP + o * 16 + c], fin[p * 16 + c], acc);
    float fo = fmaf(ws[WS_SUP + o], acc, ws[WS_CUP + o]);
    fo = fmaxf(fo, 0.f);
    float fl = fev[j] - fo;
    // Mish(x) = x*(u^2+2u)/(u^2+2u+2), u=e^x; exact for x<=15, y=x beyond
    float u = __expf(fl);
    float nmr = u * (u + 2.f);
    float y = fl * __fdividef(nmr, nmr + 2.f);
    if (fl > 15.f) y = fl;
    long long oi = ((long long)b * CC + o) * NN + n;
    if (flag) outb[oi] = __float2bfloat16(y);
    else      outf[oi] = y;
  }
}

extern "C" void kernel_launch(void* const* d_in, const int* in_sizes, int n_in,
                              void* d_out, int out_size, void* d_ws, size_t ws_size,
                              hipStream_t stream) {
  (void)in_sizes; (void)out_size; (void)ws_size;
  float* ws = (float*)d_ws;
  InPtrs ip;
  for (int i = 0; i < 22; ++i) ip.p[i] = (i < n_in) ? d_in[i] : nullptr;
  hipLaunchKernelGGL(k1_pq,        dim3(1024),         dim3(256), 0, stream, ip, ws);
  hipLaunchKernelGGL(k23_knn_fenc, dim3(BB * NN / 4),  dim3(256), 0, stream, ws);
  hipLaunchKernelGGL(k4_down,      dim3(BB * NN / 8),  dim3(256), 0, stream, ws);
  hipLaunchKernelGGL(k5_final,     dim3(BB * NN / 16), dim3(256), 0, stream, ws,
                     (float*)d_out, (__hip_bfloat16*)d_out);
}

// Round 14
// 181.660 us; speedup vs baseline: 1.0960x; 1.0509x over previous
//
#include <hip/hip_runtime.h>
#include <hip/hip_bf16.h>

#define BB 2
#define CC 128
#define NN 4096
#define KK 20

// workspace offsets, in floats
#define WS_FLAG   0
#define WS_FCACC  16
#define WS_SUP    288
#define WS_CUP    416
#define WS_FS     1024
#define WS_X      8192
#define WS_XX     32768
#define WS_WD1    57728
#define WS_WD2    59776
#define WS_WUP    61824
#define WS_P      65536
#define WS_Q      1114112
#define WS_FE     2326528
#define WS_F12    3375104

struct InPtrs { const void* p[22]; };

__device__ __forceinline__ float ldin(const void* p, long long i, int flag) {
  if (flag) {
    unsigned short b = ((const unsigned short*)p)[i];
    return __uint_as_float(((unsigned)b) << 16);
  }
  return ((const float*)p)[i];
}

// order-preserving f32 -> u32 (exact): monotone for all finite floats
__device__ __forceinline__ unsigned sortable(float v) {
  unsigned u = __float_as_uint(v);
  return (u & 0x80000000u) ? ~u : (u | 0x80000000u);
}

// wave-wide max of u32 via DPP reduction chain; uniform result via readlane 63.
__device__ __forceinline__ unsigned wave_max_u32(unsigned x) {
  unsigned t;
  t = (unsigned)__builtin_amdgcn_update_dpp(0, (int)x, 0x111, 0xF, 0xF, true); x = x > t ? x : t; // row_shr:1
  t = (unsigned)__builtin_amdgcn_update_dpp(0, (int)x, 0x112, 0xF, 0xF, true); x = x > t ? x : t; // row_shr:2
  t = (unsigned)__builtin_amdgcn_update_dpp(0, (int)x, 0x114, 0xF, 0xF, true); x = x > t ? x : t; // row_shr:4
  t = (unsigned)__builtin_amdgcn_update_dpp(0, (int)x, 0x118, 0xF, 0xF, true); x = x > t ? x : t; // row_shr:8
  t = (unsigned)__builtin_amdgcn_update_dpp(0, (int)x, 0x142, 0xF, 0xF, true); x = x > t ? x : t; // row_bcast:15
  t = (unsigned)__builtin_amdgcn_update_dpp(0, (int)x, 0x143, 0xF, 0xF, true); x = x > t ? x : t; // row_bcast:31
  return (unsigned)__builtin_amdgcn_readlane((int)x, 63);
}

// sorted-descending top-4 insert of (pd,idx); strict '>' keeps idx-ascending
// order among equal pds (stream feeds ascending idx) -> matches lax.top_k ties.
__device__ __forceinline__ void insert4p(unsigned pd, int idx,
    unsigned& p0, int& i0, unsigned& p1, int& i1,
    unsigned& p2, int& i2, unsigned& p3, int& i3) {
  bool b0 = pd > p0, b1 = pd > p1, b2 = pd > p2, b3 = pd > p3;
  p3 = b3 ? (b2 ? p2 : pd) : p3;  i3 = b3 ? (b2 ? i2 : idx) : i3;
  p2 = b2 ? (b1 ? p1 : pd) : p2;  i2 = b2 ? (b1 ? i1 : idx) : i2;
  p1 = b1 ? (b0 ? p0 : pd) : p1;  i1 = b1 ? (b0 ? i0 : idx) : i1;
  p0 = b0 ? pd : p0;              i0 = b0 ? idx : i0;
}

// ---- k1: fused staging + P,Q projections (k0 absorbed) -----------------------
// 1024 blocks = 2b x 64mt x 8ot. Per block: flag via wave ballot (bit-identical
// to the old per-thread count), 8 W2 rows staged to LDS as (P,Q) float2 pairs,
// residual global staging (X, WD1/2, WUP, SUP/CUP folds, FLAG, FCACC) done by
// blocks 0..127 before their own work.
__global__ __launch_bounds__(256) void k1_pq(InPtrs in, float* ws) {
  __shared__ float ldsW2[8 * 128 * 2];        // 8 KB: [row(8)][c(128)][P|Q]
  int t = threadIdx.x;
  int bid = blockIdx.x;              // 1024 = 2b x 64mt x 8ot
  int b = bid >> 9;
  int mt = (bid >> 3) & 63;
  int ot = bid & 7;
  int lane = t & 63;
  // flag: lane i tests word i of xyz (same predicate + count as detect_bf16)
  unsigned xw = ((const unsigned*)in.p[0])[lane];
  unsigned lo = xw & 0x7FFFu;
  unsigned long long bm = __ballot(lo >= 0x3C00u && lo <= 0x4100u);
  int flag = (__popcll(bm) >= 32) ? 1 : 0;    // wave-uniform
  // stage this block's 8 W2 rows: lds[(r*128+col)*2 + half] = W2[ot*8+r][half*128+col]
  for (int i = t; i < 2048; i += 256) {
    int r = i >> 8, cc = i & 255;
    ldsW2[((r * 128 + (cc & 127)) << 1) + (cc >> 7)] =
        ldin(in.p[8], (ot * 8 + r) * 256 + cc, flag);
  }
  // residual staging for k234/k5
  if (bid < 128) {
    int gid = bid * 256 + t;
    if      (gid < 24576) ws[WS_X   + gid]         = ldin(in.p[0],  gid,         flag);
    else if (gid < 26624) ws[WS_WD1 + gid - 24576] = ldin(in.p[14], gid - 24576, flag);
    else if (gid < 28672) ws[WS_WD2 + gid - 26624] = ldin(in.p[15], gid - 26624, flag);
    else if (gid < 30720) ws[WS_WUP + gid - 28672] = ldin(in.p[16], gid - 28672, flag);
    if (bid == 0) {
      if (t < 128) {
        float bu = ldin(in.p[17], t, flag), gu = ldin(in.p[18], t, flag);
        float beu = ldin(in.p[19], t, flag), mu = ldin(in.p[20], t, flag), vu = ldin(in.p[21], t, flag);
        float su = gu / sqrtf(vu + 1e-5f);
        ws[WS_SUP + t] = su;
        ws[WS_CUP + t] = su * (bu - mu) + beu;
      }
      if (t < 16) ws[WS_FCACC + t] = 0.f;
      if (t == 0) ((int*)ws)[WS_FLAG] = flag;
    }
  }
  __syncthreads();
  int w = __builtin_amdgcn_readfirstlane(t >> 6);
  int o0 = ot * 8 + w * 2;           // wave-uniform
  int m = (mt << 6) + lane;
  const float2* w2r0 = (const float2*)ldsW2 + (w * 2) * 128;
  const float2* w2r1 = (const float2*)ldsW2 + (w * 2 + 1) * 128;
  float accP[2] = {0.f, 0.f}, accQ[2] = {0.f, 0.f};
  long long fb = (long long)b * CC * NN + m;
#define K1_BODY(FVAL)                                  \
    {                                                  \
      float f = (FVAL);                                \
      float2 v0 = w2r0[c], v1 = w2r1[c];               \
      accP[0] = fmaf(v0.x, f, accP[0]);                \
      accQ[0] = fmaf(v0.y, f, accQ[0]);                \
      accP[1] = fmaf(v1.x, f, accP[1]);                \
      accQ[1] = fmaf(v1.y, f, accQ[1]);                \
    }
  if (flag) {
    const unsigned short* F = (const unsigned short*)in.p[1] + fb;
#pragma unroll 8
    for (int c = 0; c < 128; ++c)
      K1_BODY(__uint_as_float(((unsigned)F[(long long)c * NN]) << 16))
  } else {
    const float* F = (const float*)in.p[1] + fb;
#pragma unroll 8
    for (int c = 0; c < 128; ++c)
      K1_BODY(F[(long long)c * NN])
  }
#undef K1_BODY
  long long xb = (long long)b * 3 * NN;
  float x0 = ldin(in.p[0], xb + m, flag);
  float x1 = ldin(in.p[0], xb + NN + m, flag);
  float x2 = ldin(in.p[0], xb + 2 * NN + m, flag);
  float* P = ws + WS_P + ((long long)(b * NN + m)) * 128;
  float* Q = ws + WS_Q + ((long long)(b * NN + m)) * 128;
  float2 p1v, q1v, p2v, q2v;
#pragma unroll
  for (int j = 0; j < 2; ++j) {
    int o = o0 + j;
    float b1 = ldin(in.p[3], o, flag), g1 = ldin(in.p[4], o, flag);
    float be1 = ldin(in.p[5], o, flag), m1 = ldin(in.p[6], o, flag), v1 = ldin(in.p[7], o, flag);
    float s1 = g1 / sqrtf(v1 + 1e-5f);
    float c1 = s1 * (b1 - m1) + be1;
    float b2 = ldin(in.p[9], o, flag), g2 = ldin(in.p[10], o, flag);
    float be2 = ldin(in.p[11], o, flag), m2 = ldin(in.p[12], o, flag), v2 = ldin(in.p[13], o, flag);
    float s2 = g2 / sqrtf(v2 + 1e-5f);
    float c2 = s2 * (b2 - m2) + be2;
    float w10 = ldin(in.p[2], o * 6 + 0, flag), w11 = ldin(in.p[2], o * 6 + 1, flag);
    float w12 = ldin(in.p[2], o * 6 + 2, flag), w13 = ldin(in.p[2], o * 6 + 3, flag);
    float w14 = ldin(in.p[2], o * 6 + 4, flag), w15 = ldin(in.p[2], o * 6 + 5, flag);
    float px = fmaf(w12, x2, fmaf(w11, x1, w10 * x0));
    float qx = fmaf(w15, x2, fmaf(w14, x1, w13 * x0));
    (&p1v.x)[j] = s1 * px;
    (&q1v.x)[j] = fmaf(s1, qx - px, c1);
    (&p2v.x)[j] = s2 * accP[j];
    (&q2v.x)[j] = fmaf(s2, accQ[j] - accP[j], c2);
  }
  *(float2*)(P + o0)      = p1v;
  *(float2*)(P + 64 + o0) = p2v;
  *(float2*)(Q + o0)      = q1v;
  *(float2*)(Q + 64 + o0) = q2v;
  if (ot == 0 && w == 0) {
    float xx = __fadd_rn(__fadd_rn(__fmul_rn(x0, x0), __fmul_rn(x1, x1)), __fmul_rn(x2, x2));
    ws[WS_XX + b * NN + m] = xx;
  }
}

// ---- k234: KNN top-20 + gather/max-pool + fused down-projections (k4) --------
// KNN scan/selection/gather identical to the measured-best R8/R13 form.
// Appended k4 phase: fe also written to a 2 KB LDS tile; after a barrier,
// threads t<128 run k4's inner loop verbatim (same ldsW 129-pad layout, same
// serial c order) -> bit-identical F12/FS. FCACC via block LDS + global
// atomics, same as k4 (order-nondeterministic there too). LDS total 18.6 KB
// -> 8 blocks/CU, matching the grid's blocks-per-CU (no occupancy loss).
__global__ __launch_bounds__(256) void k234_knn_fenc_down(float* ws) {
  __shared__ float ldsFE[4 * 128];            // 2 KB
  __shared__ float ldsW[32 * 129];            // 16.5 KB
  __shared__ float ldsFC[16];
  int t = threadIdx.x;
  int w = t >> 6, lane = t & 63;
  int pt = blockIdx.x * 4 + w;                // 2048 blocks, 1 wave = 1 point
  int b = pt >> 12;                           // uniform per block
  int n = pt & (NN - 1);
  // stage W tile (same layout/order as k4)
  for (int i = t; i < 32 * 128; i += 256) {
    int o = i >> 7, c = i & 127;
    ldsW[o * 129 + c] = (o < 16) ? ws[WS_WD1 + o * 128 + c] : ws[WS_WD2 + (o - 16) * 128 + c];
  }
  if (t < 16) ldsFC[t] = 0.f;
  const float* X = ws + WS_X + (long long)b * 3 * NN;
  const float* XX = ws + WS_XX + (long long)b * NN;
  float xc0 = X[n], xc1 = X[NN + n], xc2 = X[2 * NN + n], xxn = XX[n];
  unsigned p0 = 0, p1 = 0, p2 = 0, p3 = 0;
  int i0 = 0, i1 = 0, i2 = 0, i3 = 0;
#pragma unroll 8
  for (int s = 0; s < 64; ++s) {
    int m = s * 64 + lane;
    float c0 = X[m], c1 = X[NN + m], c2 = X[2 * NN + m], xxm = XX[m];
    float inner = __fadd_rn(__fadd_rn(__fmul_rn(c0, xc0), __fmul_rn(c1, xc1)), __fmul_rn(c2, xc2));
    float pd = __fsub_rn(__fsub_rn(__fmul_rn(2.0f, inner), xxn), xxm);
    insert4p(sortable(pd), m, p0, i0, p1, i1, p2, i2, p3, i3);
  }
  unsigned long long used = 0;
  int nv = 4;
  int winner = 0;                             // lane r keeps round-r winner index
  for (int r = 0; r < KK; ++r) {
    unsigned spd = wave_max_u32(p0);          // max pd among heads (uniform)
    unsigned long long msk = __ballot(p0 == spd);
    int sidx;
    if (__popcll(msk) == 1) {                 // fast path: unique owner lane
      sidx = __builtin_amdgcn_readlane(i0, (int)(__ffsll((long long)msk) - 1));
    } else {                                  // exact-tie: min idx among ties
      unsigned cand = (p0 == spd) ? (unsigned)(4095 - i0) : 0u;
      sidx = (int)(4095u - wave_max_u32(cand));
    }
    if (lane == r) winner = sidx;
    if (p0 == spd && i0 == sidx) {            // unique owner lane pops its head
      used |= 1ull << (i0 >> 6);
      p0 = p1; i0 = i1; p1 = p2; i1 = i2; p2 = p3; i2 = i3; p3 = 0; i3 = 0;
      if (--nv == 0) {                        // rare: lane supplied >=5 winners
        p0 = p1 = p2 = p3 = 0; i0 = i1 = i2 = i3 = 0;
#pragma unroll 1
        for (int s = 0; s < 64; ++s) {
          if (!((used >> s) & 1ull)) {
            int m = s * 64 + lane;
            float c0 = X[m], c1 = X[NN + m], c2 = X[2 * NN + m], xxm = XX[m];
            float inner = __fadd_rn(__fadd_rn(__fmul_rn(c0, xc0), __fmul_rn(c1, xc1)), __fmul_rn(c2, xc2));
            float pd = __fsub_rn(__fsub_rn(__fmul_rn(2.0f, inner), xxn), xxm);
            insert4p(sortable(pd), m, p0, i0, p1, i1, p2, i2, p3, i3);
          }
        }
        nv = 4;
      }
    }
  }
  // gather + max-pool: hoist all neighbor ids first, then 20 independent loads
  const float* Q = ws + WS_Q + (long long)pt * 128;
  const float* Pb = ws + WS_P + (long long)b * NN * 128;
  float2 q = ((const float2*)Q)[lane];
  int ids[KK];
#pragma unroll
  for (int j = 0; j < KK; ++j) ids[j] = __shfl(winner, j);
  float mx0 = -3.4e38f, mx1 = -3.4e38f;
#pragma unroll
  for (int j = 0; j < KK; ++j) {
    float2 p = ((const float2*)(Pb + (long long)ids[j] * 128))[lane];
    mx0 = fmaxf(mx0, p.x + q.x);
    mx1 = fmaxf(mx1, p.y + q.y);
  }
  float2 fe = make_float2(fmaxf(mx0, 0.f), fmaxf(mx1, 0.f));
  ((float2*)(ws + WS_FE + (long long)pt * 128))[lane] = fe;
  ((float2*)(ldsFE + w * 128))[lane] = fe;
  __syncthreads();
  // ---- fused k4 phase: 4 points x 32 outputs = 128 work items ----
  if (t < 128) {
    int p = t >> 5, oid = t & 31;
    float acc = 0.f;
#pragma unroll 8
    for (int c = 0; c < 128; ++c)
      acc = fmaf(ldsW[oid * 129 + c], ldsFE[p * 128 + c], acc);
    float v = fmaxf(acc, 0.f);
    int np = (blockIdx.x * 4 + p) & (NN - 1);
    ws[WS_F12 + (long long)(b * NN + np) * 32 + oid] = v;
    if (b == 0) {
      if (oid >= 16) {
        float s = v;
#pragma unroll
        for (int d = 1; d < 16; d <<= 1) s += __shfl_xor(s, d);
        if (oid == 16) ws[WS_FS + np] = s * 0.0625f;
      } else {
        atomicAdd(&ldsFC[oid], v);
      }
    }
  }
  __syncthreads();
  if (b == 0 && t < 16) atomicAdd(ws + WS_FCACC + t, ldsFC[t]);
}

// ---------------- k5: outer-sqrt + up-proj + BN + Mish -> output --------------
__global__ __launch_bounds__(256) void k5_final(float* ws, float* outf, __hip_bfloat16* outb) {
  __shared__ float fin[16 * 16];
  int t = threadIdx.x;
  int g = t >> 4;        // 0..15 : output group of 8
  int p = t & 15;        // point within tile
  int b = blockIdx.x >> 8;
  int n0 = (blockIdx.x & 255) << 4;
  int n = n0 + p;
  int flag = ((const int*)ws)[WS_FLAG];
  {
    float fs = ws[WS_FS + n];
    float fc = ws[WS_FCACC + g] * (1.0f / NN);
    float f1v = ws[WS_F12 + (long long)(b * NN + n) * 32 + g];
    float f2v = ws[WS_F12 + (long long)(b * NN + n) * 32 + 16 + g];
    fin[p * 16 + g] = sqrtf(fc * fs + 1e-12f) + f1v + f2v;
  }
  __syncthreads();
  const float4* FE4 = (const float4*)(ws + WS_FE + (long long)(b * NN + n) * 128 + g * 8);
  float fev[8];
  {
    float4 a = FE4[0], c = FE4[1];
    fev[0] = a.x; fev[1] = a.y; fev[2] = a.z; fev[3] = a.w;
    fev[4] = c.x; fev[5] = c.y; fev[6] = c.z; fev[7] = c.w;
  }
#pragma unroll
  for (int j = 0; j < 8; ++j) {
    int o = g * 8 + j;
    float acc = 0.f;
#pragma unroll
    for (int c = 0; c < 16; ++c)
      acc = fmaf(ws[WS_WUP + o * 16 + c], fin[p * 16 + c], acc);
    float fo = fmaf(ws[WS_SUP + o], acc, ws[WS_CUP + o]);
    fo = fmaxf(fo, 0.f);
    float fl = fev[j] - fo;
    // Mish(x) = x*(u^2+2u)/(u^2+2u+2), u=e^x; exact for x<=15, y=x beyond
    float u = __expf(fl);
    float nmr = u * (u + 2.f);
    float y = fl * __fdividef(nmr, nmr + 2.f);
    if (fl > 15.f) y = fl;
    long long oi = ((long long)b * CC + o) * NN + n;
    if (flag) outb[oi] = __float2bfloat16(y);
    else      outf[oi] = y;
  }
}

extern "C" void kernel_launch(void* const* d_in, const int* in_sizes, int n_in,
                              void* d_out, int out_size, void* d_ws, size_t ws_size,
                              hipStream_t stream) {
  (void)in_sizes; (void)out_size; (void)ws_size;
  float* ws = (float*)d_ws;
  InPtrs ip;
  for (int i = 0; i < 22; ++i) ip.p[i] = (i < n_in) ? d_in[i] : nullptr;
  hipLaunchKernelGGL(k1_pq,              dim3(1024),         dim3(256), 0, stream, ip, ws);
  hipLaunchKernelGGL(k234_knn_fenc_down, dim3(BB * NN / 4),  dim3(256), 0, stream, ws);
  hipLaunchKernelGGL(k5_final,           dim3(BB * NN / 16), dim3(256), 0, stream, ws,
                     (float*)d_out, (__hip_bfloat16*)d_out);
}